// Round 2
// baseline (3828.633 us; speedup 1.0000x reference)
//
#include <hip/hip_runtime.h>

typedef unsigned int u32;
typedef unsigned short u16;
typedef unsigned long long u64;

typedef __attribute__((ext_vector_type(8))) short bf16x8;
typedef __attribute__((ext_vector_type(4))) float f32x4;

__device__ __forceinline__ u16 f2bf(float f) {
    u32 u = __float_as_uint(f);
    u += 0x7fffu + ((u >> 16) & 1u);
    return (u16)(u >> 16);
}
__device__ __forceinline__ float bf2f(u16 h) {
    return __uint_as_float(((u32)h) << 16);
}

// ---------------------------------------------------------------------------
// prep: convert/transpose weights to bf16, zero tagged h-exchange buffers
// (u32 words, tag 0 == "h_0 available, value 0")
// ---------------------------------------------------------------------------
__global__ __launch_bounds__(256) void prep_kernel(
    const float* __restrict__ W1, const float* __restrict__ W2,
    const float* __restrict__ U1, const float* __restrict__ U2,
    u16* __restrict__ W1T, u16* __restrict__ W2T,
    u16* __restrict__ U1T, u16* __restrict__ U2T,
    u32* __restrict__ hzero)
{
    int i = blockIdx.x * 256 + threadIdx.x;
    if (i < 240000) { int j = i / 200, k = i - j * 200; W1T[i] = f2bf(W1[k * 1200 + j]); return; }
    i -= 240000;
    if (i < 240000) { int j = i / 400, k = i - j * 400; W2T[i] = f2bf(W2[k * 600 + j]); return; }
    i -= 240000;
    if (i < 480000) { int j = i / 400, k = i - j * 400; U1T[i] = f2bf(U1[k * 1200 + j]); return; }
    i -= 480000;
    if (i < 120000) { int j = i / 200, k = i - j * 200; U2T[i] = f2bf(U2[k * 600 + j]); return; }
    i -= 120000;
    if (i < 153600) hzero[i] = 0u;   // both tagged h-exchange buffers
}

// ---------------------------------------------------------------------------
// embed + batchnorm -> x bf16, layout [t*128 + b][200]
// ---------------------------------------------------------------------------
__global__ __launch_bounds__(256) void embed_bn_kernel(
    const int* __restrict__ tokens, const float* __restrict__ emb,
    const float* __restrict__ gamma, const float* __restrict__ beta,
    const float* __restrict__ mmean, const float* __restrict__ mvar,
    u16* __restrict__ x)
{
    int gid = blockIdx.x * 256 + threadIdx.x;  // 6,553,600 total
    int r = gid / 200, e = gid - r * 200;
    int t = r >> 7, b = r & 127;               // r = t*128 + b
    int tok = tokens[b * 256 + t];
    float v = (emb[(size_t)tok * 200 + e] - mmean[e]) *
              (1.0f / sqrtf(mvar[e] + 1e-3f)) * gamma[e] + beta[e];
    x[gid] = f2bf(v);
}

// ---------------------------------------------------------------------------
// GEMM: C[M][N] (bf16) = A[M][KEL] (bf16) @ B[KEL][N] + bias, B given as
// BT[N][KEL]. Tile 64x64 per 256-thread WG; MFMA 16x16x32 bf16.
// ---------------------------------------------------------------------------
template<int KEL, int KSTEPS, int KPAD>
__global__ __launch_bounds__(256) void gemm_bias_kernel(
    const u16* __restrict__ A, const u16* __restrict__ BT,
    const float* __restrict__ bias, u16* __restrict__ C, int N)
{
    __shared__ u16 A_lds[64 * KPAD];
    __shared__ u16 B_lds[64 * KPAD];
    const int m0 = blockIdx.x * 64, n0 = blockIdx.y * 64;
    const int tid = threadIdx.x;
    const int lane = tid & 63, wave = tid >> 6;
    const int l15 = lane & 15, lq = lane >> 4;

    for (int idx = tid; idx < 64 * (KPAD / 2); idx += 256) {
        int row = idx / (KPAD / 2), kp = idx % (KPAD / 2);
        int k = kp * 2;
        u32 va = (k < KEL) ? *(const u32*)(A + (size_t)(m0 + row) * KEL + k) : 0u;
        *(u32*)(A_lds + row * KPAD + k) = va;
        int gn = n0 + row;
        u32 vb = (k < KEL && gn < N) ? *(const u32*)(BT + (size_t)gn * KEL + k) : 0u;
        *(u32*)(B_lds + row * KPAD + k) = vb;
    }
    __syncthreads();

    f32x4 acc[4];
    for (int i = 0; i < 4; ++i) acc[i] = (f32x4){0.f, 0.f, 0.f, 0.f};
    for (int ks = 0; ks < KSTEPS; ++ks) {
        bf16x8 a = *(const bf16x8*)(A_lds + (wave * 16 + l15) * KPAD + ks * 32 + lq * 8);
        for (int nt = 0; nt < 4; ++nt) {
            bf16x8 b = *(const bf16x8*)(B_lds + (nt * 16 + l15) * KPAD + ks * 32 + lq * 8);
            acc[nt] = __builtin_amdgcn_mfma_f32_16x16x32_bf16(a, b, acc[nt], 0, 0, 0);
        }
    }
    for (int nt = 0; nt < 4; ++nt) {
        int col = n0 + nt * 16 + l15;
        if (col < N) {
            float bv = bias[col];
            for (int i = 0; i < 4; ++i) {
                int row = m0 + wave * 16 + lq * 4 + i;
                C[(size_t)row * N + col] = f2bf(acc[nt][i] + bv);
            }
        }
    }
}

// ---------------------------------------------------------------------------
// Persistent GRU scan with SELF-TAGGED h exchange (GRU1 only now).
// h element published as u32 = (bf16 << 16) | (t+1). Poll IS the load.
// ---------------------------------------------------------------------------
template<int UH, int G, int KSTEPS, int KPAD, int HS, int NC, int NCP, int NT,
         int MAXT, int MAXE, int NH, bool WB16>
__global__ __launch_bounds__(256) void gru_kernel(
    const u16* __restrict__ xw,      // [256*128][3*UH] bf16 (row = t*128+b)
    const u16* __restrict__ UT,      // [3*UH][UH] bf16 (transposed U)
    const float* __restrict__ br,    // [3*UH] recurrent bias
    const int* __restrict__ tokens,  // [128][256]
    float* __restrict__ out_f32,     // [128][256][UH]
    u16* __restrict__ out_b16,       // [256*128][UH] or unused
    float* __restrict__ h_final,     // [128][UH]
    u32* __restrict__ hbuf)          // [8][2][16][UH] tagged u32
{
    __shared__ u16 U_lds[NCP * KPAD];
    __shared__ u16 h_lds[16 * KPAD];
    __shared__ float rec_lds[16 * NCP];

    const int wg = blockIdx.x;
    const int g = wg / G, w = wg % G;
    const int tid = threadIdx.x;
    const int b0 = g * 16;
    const int lane = tid & 63, wave = tid >> 6;
    const int l15 = lane & 15, lq = lane >> 4;

    for (int i = tid; i < NCP * KPAD / 2; i += 256) ((u32*)U_lds)[i] = 0u;
    for (int i = tid; i < 16 * KPAD / 2; i += 256) ((u32*)h_lds)[i] = 0u;
    __syncthreads();
    for (int idx = tid; idx < NC * (UH / 2); idx += 256) {
        int c = idx / (UH / 2), kp = idx % (UH / 2);
        int j = (c / HS) * UH + w * HS + (c % HS);
        u32 v = *(const u32*)(UT + (size_t)j * UH + kp * 2);
        *(u32*)(U_lds + c * KPAD + kp * 2) = v;
    }

    int ne = 0;
    int eb[MAXE], eco[MAXE], eih[MAXE], egb[MAXE], exwoff[MAXE];
    float ebrz[MAXE], ebrr[MAXE], ebrh[MAXE], hold[MAXE];
    for (int u = tid; u < 16 * HS; u += 256) {
        int b = u / HS, co = u % HS;
        int ih = w * HS + co;
        eb[ne] = b; eco[ne] = co; eih[ne] = ih; egb[ne] = b0 + b;
        exwoff[ne] = (b0 + b) * 3 * UH;
        ebrz[ne] = br[ih]; ebrr[ne] = br[UH + ih]; ebrh[ne] = br[2 * UH + ih];
        hold[ne] = 0.f;
        ++ne;
    }

    constexpr int TOT = 16 * UH / 2;   // u64 slots total
    u32 pend0 = 0;
    int soff[NH], loff[NH];
    for (int i = 0; i < NH; ++i) {
        int s = tid + i * 256;
        if (s < TOT) {
            int b = s / (UH / 2), kk = s % (UH / 2);
            soff[i] = b * UH + kk * 2;
            loff[i] = b * KPAD + kk * 2;
            pend0 |= 1u << i;
        } else { soff[i] = 0; loff[i] = 0; }
    }

    u32* hb = hbuf + (size_t)g * 2 * 16 * UH;

    for (int t = 0; t < 256; ++t) {
        float xzv[MAXE], xrv[MAXE], xhv[MAXE];
        int tokv[MAXE];
        for (int e = 0; e < ne; ++e) {
            const u16* xrow = xw + (size_t)t * (128 * 3 * UH) + exwoff[e];
            xzv[e] = bf2f(xrow[eih[e]]);
            xrv[e] = bf2f(xrow[UH + eih[e]]);
            xhv[e] = bf2f(xrow[2 * UH + eih[e]]);
            tokv[e] = tokens[egb[e] * 256 + t];
        }

        const u32* hsrc = hb + ((t + 1) & 1) * 16 * UH;
        const u32 want = (u32)t & 0xFFFFu;
        u32 pend = pend0;
        while (pend) {
            u64 tmp[NH];
            #pragma unroll
            for (int i = 0; i < NH; ++i)
                if (pend & (1u << i))
                    tmp[i] = __hip_atomic_load((const u64*)(hsrc + soff[i]),
                                               __ATOMIC_RELAXED,
                                               __HIP_MEMORY_SCOPE_AGENT);
            #pragma unroll
            for (int i = 0; i < NH; ++i)
                if (pend & (1u << i)) {
                    u64 v = tmp[i];
                    if ((u32)(v & 0xFFFFu) == want &&
                        ((u32)(v >> 32) & 0xFFFFu) == want) {
                        u32 pk = ((u32)(v >> 16) & 0xFFFFu) | ((u32)(v >> 48) << 16);
                        *(u32*)(h_lds + loff[i]) = pk;
                        pend &= ~(1u << i);
                    }
                }
            if (pend) __builtin_amdgcn_s_sleep(1);
        }
        __syncthreads();

        f32x4 acc[MAXT];
        for (int ti = 0; ti < MAXT; ++ti) acc[ti] = (f32x4){0.f, 0.f, 0.f, 0.f};
        for (int ks = 0; ks < KSTEPS; ++ks) {
            bf16x8 a = *(const bf16x8*)(h_lds + l15 * KPAD + ks * 32 + lq * 8);
            int ti = 0;
            for (int nt = wave; nt < NT; nt += 4, ++ti) {
                bf16x8 b = *(const bf16x8*)(U_lds + (nt * 16 + l15) * KPAD + ks * 32 + lq * 8);
                acc[ti] = __builtin_amdgcn_mfma_f32_16x16x32_bf16(a, b, acc[ti], 0, 0, 0);
            }
        }
        {
            int ti = 0;
            for (int nt = wave; nt < NT; nt += 4, ++ti)
                for (int i = 0; i < 4; ++i)
                    rec_lds[(lq * 4 + i) * NCP + nt * 16 + l15] = acc[ti][i];
        }
        __syncthreads();

        asm volatile("s_waitcnt vmcnt(0)" ::: "memory");

        u32* hdst = hb + (t & 1) * 16 * UH;
        for (int e = 0; e < ne; ++e) {
            int b = eb[e], co = eco[e], ih = eih[e], gb = egb[e];
            float rz = rec_lds[b * NCP + co] + ebrz[e];
            float rr = rec_lds[b * NCP + HS + co] + ebrr[e];
            float rh = rec_lds[b * NCP + 2 * HS + co] + ebrh[e];
            float z = 1.f / (1.f + __expf(-(xzv[e] + rz)));
            float r = 1.f / (1.f + __expf(-(xrv[e] + rr)));
            float pre = xhv[e] + r * rh;
            float th = 2.f / (1.f + __expf(-2.f * pre)) - 1.f;
            float hn = z * hold[e] + (1.f - z) * th;
            if (tokv[e] == 0) hn = hold[e];            // masked: carry state
            hold[e] = hn;
            u16 hv = f2bf(hn);
            u32 tagged = ((u32)hv << 16) | (u32)(t + 1);
            __hip_atomic_store(hdst + b * UH + ih, tagged, __ATOMIC_RELAXED,
                               __HIP_MEMORY_SCOPE_AGENT);
            out_f32[((size_t)gb * 256 + t) * UH + ih] = hn;
            if (WB16) out_b16[(size_t)(t * 128 + gb) * UH + ih] = hv;
            if (t == 255) h_final[(size_t)gb * UH + ih] = hn;
        }
    }
}

// ---------------------------------------------------------------------------
// GRU2, exchange-free, register-resident U2.
// One 256-thread WG per 16-batch group (8 WGs). 4 waves = 1 wave/SIMD ->
// VGPR budget 512/wave: uf[10][7] = 280 VGPRs of U2 live in registers for
// the whole scan (this is the fix for round-0's spill at 512 threads /
// VGPR_Count=128). h exchanged through LDS only, two barriers per step.
// Recurrent bias baked in via k=200 "ones" row (exact: b2 == 0).
// ---------------------------------------------------------------------------
__global__ __launch_bounds__(256, 1) void gru2_kernel(
    const u16* __restrict__ xw,      // [256*128][600] bf16 (row = t*128+b)
    const u16* __restrict__ UT,      // [600][200] bf16 (transposed U2)
    const float* __restrict__ br,    // [600] recurrent bias
    const int* __restrict__ tokens,  // [128][256]
    float* __restrict__ out_f32,     // [128][256][200]
    float* __restrict__ h_final)     // [128][200]
{
    constexpr int RSTR = 618;                // rec_lds row stride (== 2 mod 8)
    __shared__ u16 h_lds[16 * 232];          // [batch][k], k=200 holds 1.0
    __shared__ float rec_lds[16 * RSTR];     // [batch][gatecol]
    __shared__ unsigned char mask_lds[16 * 256];

    const int g = blockIdx.x;                // 8 groups of 16 batches
    const int b0 = g * 16;
    const int tid = threadIdx.x;             // 0..255 (4 waves)
    const int lane = tid & 63, wave = tid >> 6;
    const int l15 = lane & 15, lq = lane >> 4;

    // --- init: zero h_lds (incl. K pad) ---
    for (int i = tid; i < 16 * 232 / 2; i += 256) ((u32*)h_lds)[i] = 0u;
    __syncthreads();
    // ones row for bias bake-in (k = 200 stays 1.0: gates write co<200 only)
    if (tid < 16) h_lds[tid * 232 + 200] = (u16)0x3F80;   // bf16 1.0
    // token mask staging
    for (int i = tid; i < 16 * 256; i += 256) {
        int b = i >> 8, t = i & 255;
        mask_lds[i] = (tokens[(b0 + b) * 256 + t] != 0) ? 1 : 0;
    }

    // --- persistent U fragments: tile nt = wave*10+it (38 real tiles) ---
    // B-frag for mfma_16x16x32: row (gate col) = nt*16 + l15, k = ks*32+lq*8
    bf16x8 uf[10][7];
    #pragma unroll
    for (int it = 0; it < 10; ++it) {
        int nt = wave * 10 + it;
        int row = nt * 16 + l15;
        bool rv = (row < 600);
        #pragma unroll
        for (int ks = 0; ks < 7; ++ks) {
            int k0 = ks * 32 + lq * 8;
            bf16x8 v = (bf16x8){0, 0, 0, 0, 0, 0, 0, 0};
            if (rv && k0 < 200)
                v = *(const bf16x8*)(UT + (size_t)row * 200 + k0);
            if (rv && k0 == 200)
                v[0] = (short)f2bf(br[row]);             // bias row (k==200)
            uf[it][ks] = v;
        }
    }

    // --- per-thread gate elements: u = tid + e*256, u < 16*200 (MAXE=13) ---
    int be[13], ce[13];
    float hold[13];
    #pragma unroll
    for (int e = 0; e < 13; ++e) {
        int u = tid + e * 256;
        int b = u / 200;
        be[e] = b; ce[e] = u - b * 200;
        hold[e] = 0.f;
    }
    __syncthreads();

    for (int t = 0; t < 256; ++t) {
        // phase 1: prefetch gate inputs (latency overlaps MFMA below)
        float xzv[13], xrv[13], xhv[13];
        const u16* xbase = xw + (size_t)t * (128 * 600);
        #pragma unroll
        for (int e = 0; e < 13; ++e) {
            if (tid + e * 256 < 3200) {
                const u16* xrow = xbase + (size_t)(b0 + be[e]) * 600 + ce[e];
                xzv[e] = bf2f(xrow[0]);
                xrv[e] = bf2f(xrow[200]);
                xhv[e] = bf2f(xrow[400]);
            }
        }

        // phase 2: rec = [h,1] @ [U;br]  (MFMA 16x16x32, U from registers)
        f32x4 acc[10];
        #pragma unroll
        for (int it = 0; it < 10; ++it) acc[it] = (f32x4){0.f, 0.f, 0.f, 0.f};
        #pragma unroll
        for (int ks = 0; ks < 7; ++ks) {
            bf16x8 a = *(const bf16x8*)(h_lds + l15 * 232 + ks * 32 + lq * 8);
            #pragma unroll
            for (int it = 0; it < 10; ++it)
                acc[it] = __builtin_amdgcn_mfma_f32_16x16x32_bf16(a, uf[it][ks], acc[it], 0, 0, 0);
        }
        #pragma unroll
        for (int it = 0; it < 10; ++it) {
            int nt = wave * 10 + it;
            if (nt < 38) {
                #pragma unroll
                for (int i = 0; i < 4; ++i)
                    rec_lds[(lq * 4 + i) * RSTR + nt * 16 + l15] = acc[it][i];
            }
        }
        __syncthreads();

        // phase 3: gates + state update
        #pragma unroll
        for (int e = 0; e < 13; ++e) {
            if (tid + e * 256 < 3200) {
                int b = be[e], co = ce[e];
                float rz = rec_lds[b * RSTR + co];
                float rr = rec_lds[b * RSTR + 200 + co];
                float rh = rec_lds[b * RSTR + 400 + co];
                float z = 1.f / (1.f + __expf(-(xzv[e] + rz)));
                float r = 1.f / (1.f + __expf(-(xrv[e] + rr)));
                float pre = xhv[e] + r * rh;
                float th = 2.f / (1.f + __expf(-2.f * pre)) - 1.f;
                float hn = z * hold[e] + (1.f - z) * th;
                if (!mask_lds[b * 256 + t]) hn = hold[e];   // masked: carry
                hold[e] = hn;
                h_lds[b * 232 + co] = f2bf(hn);
                out_f32[((size_t)(b0 + b) * 256 + t) * 200 + co] = hn;
                if (t == 255) h_final[(size_t)(b0 + b) * 200 + co] = hn;
            }
        }
        __syncthreads();
    }
}

// ---------------------------------------------------------------------------
// launch
// ---------------------------------------------------------------------------
extern "C" void kernel_launch(void* const* d_in, const int* in_sizes, int n_in,
                              void* d_out, int out_size, void* d_ws, size_t ws_size,
                              hipStream_t stream)
{
    const int*   tokens = (const int*)d_in[0];
    const float* emb    = (const float*)d_in[1];
    const float* gamma  = (const float*)d_in[2];
    const float* beta   = (const float*)d_in[3];
    const float* mmean  = (const float*)d_in[4];
    const float* mvar   = (const float*)d_in[5];
    const float* W1     = (const float*)d_in[6];
    const float* U1     = (const float*)d_in[7];
    const float* b1     = (const float*)d_in[8];
    const float* W2     = (const float*)d_in[9];
    const float* U2     = (const float*)d_in[10];
    const float* b2     = (const float*)d_in[11];

    float* out = (float*)d_out;
    char* ws = (char*)d_ws;

    u16* x     = (u16*)(ws + 0);            // 32768*200*2  = 13,107,200
    u16* xw1   = (u16*)(ws + 13107200);     // 32768*1200*2 = 78,643,200
    u16* o1b   = (u16*)(ws + 91750400);     // 32768*400*2  = 26,214,400
    u16* xw2   = (u16*)(ws + 117964800);    // 32768*600*2  = 39,321,600
    u16* W1T   = (u16*)(ws + 157286400);    // 480,000
    u16* W2T   = (u16*)(ws + 157766400);    // 480,000
    u16* U1T   = (u16*)(ws + 158246400);    // 960,000
    u16* U2T   = (u16*)(ws + 159206400);    // 240,000
    u32* hbuf1 = (u32*)(ws + 159446400);    // 8*2*16*400 u32 = 409,600 B
    u32* hbuf2 = (u32*)(ws + 159856000);    // 8*2*16*200 u32 = 204,800 B (unused)

    float* out2 = out;              // [128,256,200]
    float* out1 = out + 6553600;    // [128,256,400]
    float* h2   = out + 19660800;   // [128,200]
    float* h1   = out + 19686400;   // [128,400]

    prep_kernel<<<4819, 256, 0, stream>>>(W1, W2, U1, U2, W1T, W2T, U1T, U2T,
                                          hbuf1);
    embed_bn_kernel<<<25600, 256, 0, stream>>>(tokens, emb, gamma, beta, mmean,
                                               mvar, x);
    // xw1 = x @ W1 + bi1   ([32768,200]@[200,1200])
    gemm_bias_kernel<200, 7, 232><<<dim3(512, 19), 256, 0, stream>>>(
        x, W1T, b1, xw1, 1200);
    // GRU1: UH=400, G=16 (128 WGs), HS=25, NT=5, NH=13 (3200 u64 slots)
    gru_kernel<400, 16, 13, 424, 25, 75, 80, 5, 2, 2, 13, true><<<128, 256, 0, stream>>>(
        xw1, U1T, b1 + 1200, tokens, out1, o1b, h1, hbuf1);
    // xw2 = out1 @ W2 + bi2   ([32768,400]@[400,600])
    gemm_bias_kernel<400, 13, 424><<<dim3(512, 10), 256, 0, stream>>>(
        o1b, W2T, b2, xw2, 600);
    // GRU2: exchange-free, 8 WGs x 256 threads, register-resident U2
    gru2_kernel<<<8, 256, 0, stream>>>(xw2, U2T, b2 + 600, tokens, out2, h2);
    (void)hbuf2;
}

// Round 3
// 3456.547 us; speedup vs baseline: 1.1076x; 1.1076x over previous
//
#include <hip/hip_runtime.h>

typedef unsigned int u32;
typedef unsigned short u16;
typedef unsigned long long u64;

typedef __attribute__((ext_vector_type(8))) short bf16x8;
typedef __attribute__((ext_vector_type(4))) float f32x4;

__device__ __forceinline__ u16 f2bf(float f) {
    u32 u = __float_as_uint(f);
    u += 0x7fffu + ((u >> 16) & 1u);
    return (u16)(u >> 16);
}
__device__ __forceinline__ float bf2f(u16 h) {
    return __uint_as_float(((u32)h) << 16);
}

// ---------------------------------------------------------------------------
// prep: convert/transpose weights to bf16, zero tagged h-exchange buffers
// AND the XCD-claim counters (16 u32 appended after hbuf2).
// ---------------------------------------------------------------------------
__global__ __launch_bounds__(256) void prep_kernel(
    const float* __restrict__ W1, const float* __restrict__ W2,
    const float* __restrict__ U1, const float* __restrict__ U2,
    u16* __restrict__ W1T, u16* __restrict__ W2T,
    u16* __restrict__ U1T, u16* __restrict__ U2T,
    u32* __restrict__ hzero)
{
    int i = blockIdx.x * 256 + threadIdx.x;
    if (i < 240000) { int j = i / 200, k = i - j * 200; W1T[i] = f2bf(W1[k * 1200 + j]); return; }
    i -= 240000;
    if (i < 240000) { int j = i / 400, k = i - j * 400; W2T[i] = f2bf(W2[k * 600 + j]); return; }
    i -= 240000;
    if (i < 480000) { int j = i / 400, k = i - j * 400; U1T[i] = f2bf(U1[k * 1200 + j]); return; }
    i -= 480000;
    if (i < 120000) { int j = i / 200, k = i - j * 200; U2T[i] = f2bf(U2[k * 600 + j]); return; }
    i -= 120000;
    if (i < 153616) hzero[i] = 0u;   // hbuf1 + hbuf2 + claims1 + claims2
}

// ---------------------------------------------------------------------------
// embed + batchnorm -> x bf16, layout [t*128 + b][200]
// ---------------------------------------------------------------------------
__global__ __launch_bounds__(256) void embed_bn_kernel(
    const int* __restrict__ tokens, const float* __restrict__ emb,
    const float* __restrict__ gamma, const float* __restrict__ beta,
    const float* __restrict__ mmean, const float* __restrict__ mvar,
    u16* __restrict__ x)
{
    int gid = blockIdx.x * 256 + threadIdx.x;  // 6,553,600 total
    int r = gid / 200, e = gid - r * 200;
    int t = r >> 7, b = r & 127;               // r = t*128 + b
    int tok = tokens[b * 256 + t];
    float v = (emb[(size_t)tok * 200 + e] - mmean[e]) *
              (1.0f / sqrtf(mvar[e] + 1e-3f)) * gamma[e] + beta[e];
    x[gid] = f2bf(v);
}

// ---------------------------------------------------------------------------
// GEMM: C[M][N] (bf16) = A[M][KEL] (bf16) @ B[KEL][N] + bias, B given as
// BT[N][KEL]. Tile 64x64 per 256-thread WG; MFMA 16x16x32 bf16.
// ---------------------------------------------------------------------------
template<int KEL, int KSTEPS, int KPAD>
__global__ __launch_bounds__(256) void gemm_bias_kernel(
    const u16* __restrict__ A, const u16* __restrict__ BT,
    const float* __restrict__ bias, u16* __restrict__ C, int N)
{
    __shared__ u16 A_lds[64 * KPAD];
    __shared__ u16 B_lds[64 * KPAD];
    const int m0 = blockIdx.x * 64, n0 = blockIdx.y * 64;
    const int tid = threadIdx.x;
    const int lane = tid & 63, wave = tid >> 6;
    const int l15 = lane & 15, lq = lane >> 4;

    for (int idx = tid; idx < 64 * (KPAD / 2); idx += 256) {
        int row = idx / (KPAD / 2), kp = idx % (KPAD / 2);
        int k = kp * 2;
        u32 va = (k < KEL) ? *(const u32*)(A + (size_t)(m0 + row) * KEL + k) : 0u;
        *(u32*)(A_lds + row * KPAD + k) = va;
        int gn = n0 + row;
        u32 vb = (k < KEL && gn < N) ? *(const u32*)(BT + (size_t)gn * KEL + k) : 0u;
        *(u32*)(B_lds + row * KPAD + k) = vb;
    }
    __syncthreads();

    f32x4 acc[4];
    for (int i = 0; i < 4; ++i) acc[i] = (f32x4){0.f, 0.f, 0.f, 0.f};
    for (int ks = 0; ks < KSTEPS; ++ks) {
        bf16x8 a = *(const bf16x8*)(A_lds + (wave * 16 + l15) * KPAD + ks * 32 + lq * 8);
        for (int nt = 0; nt < 4; ++nt) {
            bf16x8 b = *(const bf16x8*)(B_lds + (nt * 16 + l15) * KPAD + ks * 32 + lq * 8);
            acc[nt] = __builtin_amdgcn_mfma_f32_16x16x32_bf16(a, b, acc[nt], 0, 0, 0);
        }
    }
    for (int nt = 0; nt < 4; ++nt) {
        int col = n0 + nt * 16 + l15;
        if (col < N) {
            float bv = bias[col];
            for (int i = 0; i < 4; ++i) {
                int row = m0 + wave * 16 + lq * 4 + i;
                C[(size_t)row * N + col] = f2bf(acc[nt][i] + bv);
            }
        }
    }
}

// ---------------------------------------------------------------------------
// Persistent GRU scan with SELF-TAGGED h exchange + XCD-affinity claiming.
// h element published as u32 = (bf16 << 16) | (t+1). Poll IS the load.
// Each WG reads HW_REG_XCC_ID and claims a (group, slot) preferring
// group == own XCD -> all partners of a group share one XCD's L2, turning
// the exchange round trip from cross-fabric into local-L2.
// Claim scan is deadlock-free under any WG->XCD mapping (counting argument).
// ---------------------------------------------------------------------------
template<int UH, int G, int KSTEPS, int KPAD, int HS, int NC, int NCP, int NT,
         int MAXT, int MAXE, int NH, bool WB16>
__global__ __launch_bounds__(256) void gru_kernel(
    const u16* __restrict__ xw,      // [256*128][3*UH] bf16 (row = t*128+b)
    const u16* __restrict__ UT,      // [3*UH][UH] bf16 (transposed U)
    const float* __restrict__ br,    // [3*UH] recurrent bias
    const int* __restrict__ tokens,  // [128][256]
    float* __restrict__ out_f32,     // [128][256][UH]
    u16* __restrict__ out_b16,       // [256*128][UH] or unused
    float* __restrict__ h_final,     // [128][UH]
    u32* __restrict__ hbuf,          // [8][2][16][UH] tagged u32
    u32* __restrict__ claims)        // [8] claim counters (zeroed by prep)
{
    __shared__ u16 U_lds[NCP * KPAD];
    __shared__ u16 h_lds[16 * KPAD];
    __shared__ float rec_lds[16 * NCP];
    __shared__ int claim_s[2];

    const int tid = threadIdx.x;

    // --- XCD-affinity claim (one per WG) ---
    if (tid == 0) {
        u32 xcc;
        asm volatile("s_getreg_b32 %0, hwreg(HW_REG_XCC_ID)" : "=s"(xcc));
        int x = (int)(xcc & 7u);
        int cg = -1, cw = -1;
        for (int a = 0; a < 8; ++a) {
            int gg = (x + a) & 7;
            u32 ww = atomicAdd(&claims[gg], 1u);
            if (ww < (u32)G) { cg = gg; cw = (int)ww; break; }
        }
        claim_s[0] = cg; claim_s[1] = cw;
    }
    __syncthreads();
    const int g = claim_s[0], w = claim_s[1];

    const int b0 = g * 16;
    const int lane = tid & 63, wave = tid >> 6;
    const int l15 = lane & 15, lq = lane >> 4;

    for (int i = tid; i < NCP * KPAD / 2; i += 256) ((u32*)U_lds)[i] = 0u;
    for (int i = tid; i < 16 * KPAD / 2; i += 256) ((u32*)h_lds)[i] = 0u;
    __syncthreads();
    for (int idx = tid; idx < NC * (UH / 2); idx += 256) {
        int c = idx / (UH / 2), kp = idx % (UH / 2);
        int j = (c / HS) * UH + w * HS + (c % HS);
        u32 v = *(const u32*)(UT + (size_t)j * UH + kp * 2);
        *(u32*)(U_lds + c * KPAD + kp * 2) = v;
    }

    int ne = 0;
    int eb[MAXE], eco[MAXE], eih[MAXE], egb[MAXE], exwoff[MAXE];
    float ebrz[MAXE], ebrr[MAXE], ebrh[MAXE], hold[MAXE];
    for (int u = tid; u < 16 * HS; u += 256) {
        int b = u / HS, co = u % HS;
        int ih = w * HS + co;
        eb[ne] = b; eco[ne] = co; eih[ne] = ih; egb[ne] = b0 + b;
        exwoff[ne] = (b0 + b) * 3 * UH;
        ebrz[ne] = br[ih]; ebrr[ne] = br[UH + ih]; ebrh[ne] = br[2 * UH + ih];
        hold[ne] = 0.f;
        ++ne;
    }

    constexpr int TOT = 16 * UH / 2;   // u64 slots total
    u32 pend0 = 0;
    int soff[NH], loff[NH];
    for (int i = 0; i < NH; ++i) {
        int s = tid + i * 256;
        if (s < TOT) {
            int b = s / (UH / 2), kk = s % (UH / 2);
            soff[i] = b * UH + kk * 2;
            loff[i] = b * KPAD + kk * 2;
            pend0 |= 1u << i;
        } else { soff[i] = 0; loff[i] = 0; }
    }

    u32* hb = hbuf + (size_t)g * 2 * 16 * UH;

    for (int t = 0; t < 256; ++t) {
        float xzv[MAXE], xrv[MAXE], xhv[MAXE];
        int tokv[MAXE];
        for (int e = 0; e < ne; ++e) {
            const u16* xrow = xw + (size_t)t * (128 * 3 * UH) + exwoff[e];
            xzv[e] = bf2f(xrow[eih[e]]);
            xrv[e] = bf2f(xrow[UH + eih[e]]);
            xhv[e] = bf2f(xrow[2 * UH + eih[e]]);
            tokv[e] = tokens[egb[e] * 256 + t];
        }

        const u32* hsrc = hb + ((t + 1) & 1) * 16 * UH;
        const u32 want = (u32)t & 0xFFFFu;
        u32 pend = pend0;
        while (pend) {
            u64 tmp[NH];
            #pragma unroll
            for (int i = 0; i < NH; ++i)
                if (pend & (1u << i))
                    tmp[i] = __hip_atomic_load((const u64*)(hsrc + soff[i]),
                                               __ATOMIC_RELAXED,
                                               __HIP_MEMORY_SCOPE_AGENT);
            #pragma unroll
            for (int i = 0; i < NH; ++i)
                if (pend & (1u << i)) {
                    u64 v = tmp[i];
                    if ((u32)(v & 0xFFFFu) == want &&
                        ((u32)(v >> 32) & 0xFFFFu) == want) {
                        u32 pk = ((u32)(v >> 16) & 0xFFFFu) | ((u32)(v >> 48) << 16);
                        *(u32*)(h_lds + loff[i]) = pk;
                        pend &= ~(1u << i);
                    }
                }
            if (pend) __builtin_amdgcn_s_sleep(1);
        }
        __syncthreads();

        f32x4 acc[MAXT];
        for (int ti = 0; ti < MAXT; ++ti) acc[ti] = (f32x4){0.f, 0.f, 0.f, 0.f};
        for (int ks = 0; ks < KSTEPS; ++ks) {
            bf16x8 a = *(const bf16x8*)(h_lds + l15 * KPAD + ks * 32 + lq * 8);
            int ti = 0;
            for (int nt = wave; nt < NT; nt += 4, ++ti) {
                bf16x8 b = *(const bf16x8*)(U_lds + (nt * 16 + l15) * KPAD + ks * 32 + lq * 8);
                acc[ti] = __builtin_amdgcn_mfma_f32_16x16x32_bf16(a, b, acc[ti], 0, 0, 0);
            }
        }
        {
            int ti = 0;
            for (int nt = wave; nt < NT; nt += 4, ++ti)
                for (int i = 0; i < 4; ++i)
                    rec_lds[(lq * 4 + i) * NCP + nt * 16 + l15] = acc[ti][i];
        }
        __syncthreads();

        asm volatile("s_waitcnt vmcnt(0)" ::: "memory");

        u32* hdst = hb + (t & 1) * 16 * UH;
        for (int e = 0; e < ne; ++e) {
            int b = eb[e], co = eco[e], ih = eih[e], gb = egb[e];
            float rz = rec_lds[b * NCP + co] + ebrz[e];
            float rr = rec_lds[b * NCP + HS + co] + ebrr[e];
            float rh = rec_lds[b * NCP + 2 * HS + co] + ebrh[e];
            float z = 1.f / (1.f + __expf(-(xzv[e] + rz)));
            float r = 1.f / (1.f + __expf(-(xrv[e] + rr)));
            float pre = xhv[e] + r * rh;
            float th = 2.f / (1.f + __expf(-2.f * pre)) - 1.f;
            float hn = z * hold[e] + (1.f - z) * th;
            if (tokv[e] == 0) hn = hold[e];            // masked: carry state
            hold[e] = hn;
            u16 hv = f2bf(hn);
            u32 tagged = ((u32)hv << 16) | (u32)(t + 1);
            __hip_atomic_store(hdst + b * UH + ih, tagged, __ATOMIC_RELAXED,
                               __HIP_MEMORY_SCOPE_AGENT);
            out_f32[((size_t)gb * 256 + t) * UH + ih] = hn;
            if (WB16) out_b16[(size_t)(t * 128 + gb) * UH + ih] = hv;
            if (t == 255) h_final[(size_t)gb * UH + ih] = hn;
        }
    }
}

// ---------------------------------------------------------------------------
// launch
// ---------------------------------------------------------------------------
extern "C" void kernel_launch(void* const* d_in, const int* in_sizes, int n_in,
                              void* d_out, int out_size, void* d_ws, size_t ws_size,
                              hipStream_t stream)
{
    const int*   tokens = (const int*)d_in[0];
    const float* emb    = (const float*)d_in[1];
    const float* gamma  = (const float*)d_in[2];
    const float* beta   = (const float*)d_in[3];
    const float* mmean  = (const float*)d_in[4];
    const float* mvar   = (const float*)d_in[5];
    const float* W1     = (const float*)d_in[6];
    const float* U1     = (const float*)d_in[7];
    const float* b1     = (const float*)d_in[8];
    const float* W2     = (const float*)d_in[9];
    const float* U2     = (const float*)d_in[10];
    const float* b2     = (const float*)d_in[11];

    float* out = (float*)d_out;
    char* ws = (char*)d_ws;

    u16* x     = (u16*)(ws + 0);            // 32768*200*2  = 13,107,200
    u16* xw1   = (u16*)(ws + 13107200);     // 32768*1200*2 = 78,643,200
    u16* o1b   = (u16*)(ws + 91750400);     // 32768*400*2  = 26,214,400
    u16* xw2   = (u16*)(ws + 117964800);    // 32768*600*2  = 39,321,600
    u16* W1T   = (u16*)(ws + 157286400);    // 480,000
    u16* W2T   = (u16*)(ws + 157766400);    // 480,000
    u16* U1T   = (u16*)(ws + 158246400);    // 960,000
    u16* U2T   = (u16*)(ws + 159206400);    // 240,000
    u32* hbuf1 = (u32*)(ws + 159446400);    // 8*2*16*400 u32 = 409,600 B
    u32* hbuf2 = (u32*)(ws + 159856000);    // 8*2*16*200 u32 = 204,800 B
    u32* clm1  = (u32*)(ws + 160060800);    // 8 u32
    u32* clm2  = (u32*)(ws + 160060832);    // 8 u32

    float* out2 = out;              // [128,256,200]
    float* out1 = out + 6553600;    // [128,256,400]
    float* h2   = out + 19660800;   // [128,200]
    float* h1   = out + 19686400;   // [128,400]

    prep_kernel<<<4819, 256, 0, stream>>>(W1, W2, U1, U2, W1T, W2T, U1T, U2T,
                                          hbuf1);
    embed_bn_kernel<<<25600, 256, 0, stream>>>(tokens, emb, gamma, beta, mmean,
                                               mvar, x);
    // xw1 = x @ W1 + bi1   ([32768,200]@[200,1200])
    gemm_bias_kernel<200, 7, 232><<<dim3(512, 19), 256, 0, stream>>>(
        x, W1T, b1, xw1, 1200);
    // GRU1: UH=400, G=16 (128 WGs), HS=25, NT=5, NH=13 (3200 u64 slots)
    gru_kernel<400, 16, 13, 424, 25, 75, 80, 5, 2, 2, 13, true><<<128, 256, 0, stream>>>(
        xw1, U1T, b1 + 1200, tokens, out1, o1b, h1, hbuf1, clm1);
    // xw2 = out1 @ W2 + bi2   ([32768,400]@[400,600])
    gemm_bias_kernel<400, 13, 424><<<dim3(512, 10), 256, 0, stream>>>(
        o1b, W2T, b2, xw2, 600);
    // GRU2: UH=200, G=4 (32 WGs), HS=50, NT=10, NH=7 (1600 u64 slots)
    gru_kernel<200, 4, 7, 232, 50, 150, 160, 10, 3, 4, 7, false><<<32, 256, 0, stream>>>(
        xw2, U2T, b2 + 600, tokens, out2, (u16*)nullptr, h2, hbuf2, clm2);
}

// Round 4
// 3447.358 us; speedup vs baseline: 1.1106x; 1.0027x over previous
//
#include <hip/hip_runtime.h>

typedef unsigned int u32;
typedef unsigned short u16;
typedef unsigned long long u64;

typedef __attribute__((ext_vector_type(8))) short bf16x8;
typedef __attribute__((ext_vector_type(4))) float f32x4;

__device__ __forceinline__ u16 f2bf(float f) {
    u32 u = __float_as_uint(f);
    u += 0x7fffu + ((u >> 16) & 1u);
    return (u16)(u >> 16);
}
__device__ __forceinline__ float bf2f(u16 h) {
    return __uint_as_float(((u32)h) << 16);
}

// ---------------------------------------------------------------------------
// prep: convert/transpose weights to bf16, zero tagged h-exchange rings
// (depth-4) AND the XCD-claim counters. Zero extent:
// hbuf1 204,800 u32 + hbuf2 102,400 u32 + 16 claim u32 = 307,216.
// ---------------------------------------------------------------------------
__global__ __launch_bounds__(256) void prep_kernel(
    const float* __restrict__ W1, const float* __restrict__ W2,
    const float* __restrict__ U1, const float* __restrict__ U2,
    u16* __restrict__ W1T, u16* __restrict__ W2T,
    u16* __restrict__ U1T, u16* __restrict__ U2T,
    u32* __restrict__ hzero)
{
    int i = blockIdx.x * 256 + threadIdx.x;
    if (i < 240000) { int j = i / 200, k = i - j * 200; W1T[i] = f2bf(W1[k * 1200 + j]); return; }
    i -= 240000;
    if (i < 240000) { int j = i / 400, k = i - j * 400; W2T[i] = f2bf(W2[k * 600 + j]); return; }
    i -= 240000;
    if (i < 480000) { int j = i / 400, k = i - j * 400; U1T[i] = f2bf(U1[k * 1200 + j]); return; }
    i -= 480000;
    if (i < 120000) { int j = i / 200, k = i - j * 200; U2T[i] = f2bf(U2[k * 600 + j]); return; }
    i -= 120000;
    if (i < 307216) hzero[i] = 0u;   // hbuf1 + hbuf2 + claims1 + claims2
}

// ---------------------------------------------------------------------------
// embed + batchnorm -> x bf16, layout [t*128 + b][200]
// ---------------------------------------------------------------------------
__global__ __launch_bounds__(256) void embed_bn_kernel(
    const int* __restrict__ tokens, const float* __restrict__ emb,
    const float* __restrict__ gamma, const float* __restrict__ beta,
    const float* __restrict__ mmean, const float* __restrict__ mvar,
    u16* __restrict__ x)
{
    int gid = blockIdx.x * 256 + threadIdx.x;  // 6,553,600 total
    int r = gid / 200, e = gid - r * 200;
    int t = r >> 7, b = r & 127;               // r = t*128 + b
    int tok = tokens[b * 256 + t];
    float v = (emb[(size_t)tok * 200 + e] - mmean[e]) *
              (1.0f / sqrtf(mvar[e] + 1e-3f)) * gamma[e] + beta[e];
    x[gid] = f2bf(v);
}

// ---------------------------------------------------------------------------
// GEMM: C[M][N] (bf16) = A[M][KEL] (bf16) @ B[KEL][N] + bias, B given as
// BT[N][KEL]. Tile 64x64 per 256-thread WG; MFMA 16x16x32 bf16.
// ---------------------------------------------------------------------------
template<int KEL, int KSTEPS, int KPAD>
__global__ __launch_bounds__(256) void gemm_bias_kernel(
    const u16* __restrict__ A, const u16* __restrict__ BT,
    const float* __restrict__ bias, u16* __restrict__ C, int N)
{
    __shared__ u16 A_lds[64 * KPAD];
    __shared__ u16 B_lds[64 * KPAD];
    const int m0 = blockIdx.x * 64, n0 = blockIdx.y * 64;
    const int tid = threadIdx.x;
    const int lane = tid & 63, wave = tid >> 6;
    const int l15 = lane & 15, lq = lane >> 4;

    for (int idx = tid; idx < 64 * (KPAD / 2); idx += 256) {
        int row = idx / (KPAD / 2), kp = idx % (KPAD / 2);
        int k = kp * 2;
        u32 va = (k < KEL) ? *(const u32*)(A + (size_t)(m0 + row) * KEL + k) : 0u;
        *(u32*)(A_lds + row * KPAD + k) = va;
        int gn = n0 + row;
        u32 vb = (k < KEL && gn < N) ? *(const u32*)(BT + (size_t)gn * KEL + k) : 0u;
        *(u32*)(B_lds + row * KPAD + k) = vb;
    }
    __syncthreads();

    f32x4 acc[4];
    for (int i = 0; i < 4; ++i) acc[i] = (f32x4){0.f, 0.f, 0.f, 0.f};
    for (int ks = 0; ks < KSTEPS; ++ks) {
        bf16x8 a = *(const bf16x8*)(A_lds + (wave * 16 + l15) * KPAD + ks * 32 + lq * 8);
        for (int nt = 0; nt < 4; ++nt) {
            bf16x8 b = *(const bf16x8*)(B_lds + (nt * 16 + l15) * KPAD + ks * 32 + lq * 8);
            acc[nt] = __builtin_amdgcn_mfma_f32_16x16x32_bf16(a, b, acc[nt], 0, 0, 0);
        }
    }
    for (int nt = 0; nt < 4; ++nt) {
        int col = n0 + nt * 16 + l15;
        if (col < N) {
            float bv = bias[col];
            for (int i = 0; i < 4; ++i) {
                int row = m0 + wave * 16 + lq * 4 + i;
                C[(size_t)row * N + col] = f2bf(acc[nt][i] + bv);
            }
        }
    }
}

// ---------------------------------------------------------------------------
// Persistent GRU scan, SELF-TAGGED h exchange, DEPTH-4 ring (NO per-step
// waitcnt). h element published as u32 = (bf16 << 16) | (t+1); consumer of
// step t polls slot (t & 3) for exact tag t. Tags are unique per t, so a
// stale slot (tag t-4) can never satisfy a poll.
// WAR safety WITHOUT a fence: two stores to the same ring address are 4
// steps apart; each thread issues >=27 VMEM ops per step (>=108 between
// reuses) > the 63-entry vmcnt window, and vmcnt retires in order, so the
// old store has provably retired before the new one issues.
// XCD-affinity claiming (HW_REG_XCC_ID + ring-scan atomics) keeps a group's
// WGs on one XCD: proven to cut HBM fetch 3x (round 3).
// ---------------------------------------------------------------------------
template<int UH, int G, int KSTEPS, int KPAD, int HS, int NC, int NCP, int NT,
         int MAXT, int MAXE, int NH, bool WB16>
__global__ __launch_bounds__(256) void gru_kernel(
    const u16* __restrict__ xw,      // [256*128][3*UH] bf16 (row = t*128+b)
    const u16* __restrict__ UT,      // [3*UH][UH] bf16 (transposed U)
    const float* __restrict__ br,    // [3*UH] recurrent bias
    const int* __restrict__ tokens,  // [128][256]
    float* __restrict__ out_f32,     // [128][256][UH]
    u16* __restrict__ out_b16,       // [256*128][UH] or unused
    float* __restrict__ h_final,     // [128][UH]
    u32* __restrict__ hbuf,          // [8][4][16][UH] tagged u32
    u32* __restrict__ claims)        // [8] claim counters (zeroed by prep)
{
    __shared__ u16 U_lds[NCP * KPAD];
    __shared__ u16 h_lds[16 * KPAD];
    __shared__ float rec_lds[16 * NCP];
    __shared__ int claim_s[2];

    const int tid = threadIdx.x;

    // --- XCD-affinity claim (one per WG) ---
    if (tid == 0) {
        u32 xcc;
        asm volatile("s_getreg_b32 %0, hwreg(HW_REG_XCC_ID)" : "=s"(xcc));
        int x = (int)(xcc & 7u);
        int cg = -1, cw = -1;
        for (int a = 0; a < 8; ++a) {
            int gg = (x + a) & 7;
            u32 ww = atomicAdd(&claims[gg], 1u);
            if (ww < (u32)G) { cg = gg; cw = (int)ww; break; }
        }
        claim_s[0] = cg; claim_s[1] = cw;
    }
    __syncthreads();
    const int g = claim_s[0], w = claim_s[1];

    const int b0 = g * 16;
    const int lane = tid & 63, wave = tid >> 6;
    const int l15 = lane & 15, lq = lane >> 4;

    for (int i = tid; i < NCP * KPAD / 2; i += 256) ((u32*)U_lds)[i] = 0u;
    for (int i = tid; i < 16 * KPAD / 2; i += 256) ((u32*)h_lds)[i] = 0u;
    __syncthreads();
    for (int idx = tid; idx < NC * (UH / 2); idx += 256) {
        int c = idx / (UH / 2), kp = idx % (UH / 2);
        int j = (c / HS) * UH + w * HS + (c % HS);
        u32 v = *(const u32*)(UT + (size_t)j * UH + kp * 2);
        *(u32*)(U_lds + c * KPAD + kp * 2) = v;
    }

    int ne = 0;
    int eb[MAXE], eco[MAXE], eih[MAXE], egb[MAXE], exwoff[MAXE];
    float ebrz[MAXE], ebrr[MAXE], ebrh[MAXE], hold[MAXE];
    for (int u = tid; u < 16 * HS; u += 256) {
        int b = u / HS, co = u % HS;
        int ih = w * HS + co;
        eb[ne] = b; eco[ne] = co; eih[ne] = ih; egb[ne] = b0 + b;
        exwoff[ne] = (b0 + b) * 3 * UH;
        ebrz[ne] = br[ih]; ebrr[ne] = br[UH + ih]; ebrh[ne] = br[2 * UH + ih];
        hold[ne] = 0.f;
        ++ne;
    }

    constexpr int TOT = 16 * UH / 2;   // u64 slots total
    u32 pend0 = 0;
    int soff[NH], loff[NH];
    for (int i = 0; i < NH; ++i) {
        int s = tid + i * 256;
        if (s < TOT) {
            int b = s / (UH / 2), kk = s % (UH / 2);
            soff[i] = b * UH + kk * 2;
            loff[i] = b * KPAD + kk * 2;
            pend0 |= 1u << i;
        } else { soff[i] = 0; loff[i] = 0; }
    }

    u32* hb = hbuf + (size_t)g * 4 * 16 * UH;

    for (int t = 0; t < 256; ++t) {
        float xzv[MAXE], xrv[MAXE], xhv[MAXE];
        int tokv[MAXE];
        for (int e = 0; e < ne; ++e) {
            const u16* xrow = xw + (size_t)t * (128 * 3 * UH) + exwoff[e];
            xzv[e] = bf2f(xrow[eih[e]]);
            xrv[e] = bf2f(xrow[UH + eih[e]]);
            xhv[e] = bf2f(xrow[2 * UH + eih[e]]);
            tokv[e] = tokens[egb[e] * 256 + t];
        }

        const u32* hsrc = hb + (t & 3) * 16 * UH;
        const u32 want = (u32)t & 0xFFFFu;
        u32 pend = pend0;
        while (pend) {
            u64 tmp[NH];
            #pragma unroll
            for (int i = 0; i < NH; ++i)
                if (pend & (1u << i))
                    tmp[i] = __hip_atomic_load((const u64*)(hsrc + soff[i]),
                                               __ATOMIC_RELAXED,
                                               __HIP_MEMORY_SCOPE_AGENT);
            #pragma unroll
            for (int i = 0; i < NH; ++i)
                if (pend & (1u << i)) {
                    u64 v = tmp[i];
                    if ((u32)(v & 0xFFFFu) == want &&
                        ((u32)(v >> 32) & 0xFFFFu) == want) {
                        u32 pk = ((u32)(v >> 16) & 0xFFFFu) | ((u32)(v >> 48) << 16);
                        *(u32*)(h_lds + loff[i]) = pk;
                        pend &= ~(1u << i);
                    }
                }
            if (pend) __builtin_amdgcn_s_sleep(1);
        }
        __syncthreads();

        f32x4 acc[MAXT];
        for (int ti = 0; ti < MAXT; ++ti) acc[ti] = (f32x4){0.f, 0.f, 0.f, 0.f};
        for (int ks = 0; ks < KSTEPS; ++ks) {
            bf16x8 a = *(const bf16x8*)(h_lds + l15 * KPAD + ks * 32 + lq * 8);
            int ti = 0;
            for (int nt = wave; nt < NT; nt += 4, ++ti) {
                bf16x8 b = *(const bf16x8*)(U_lds + (nt * 16 + l15) * KPAD + ks * 32 + lq * 8);
                acc[ti] = __builtin_amdgcn_mfma_f32_16x16x32_bf16(a, b, acc[ti], 0, 0, 0);
            }
        }
        {
            int ti = 0;
            for (int nt = wave; nt < NT; nt += 4, ++ti)
                for (int i = 0; i < 4; ++i)
                    rec_lds[(lq * 4 + i) * NCP + nt * 16 + l15] = acc[ti][i];
        }
        __syncthreads();

        // NOTE: no vmcnt(0) here. Depth-4 ring + in-order vmcnt retirement
        // makes the same-address store-store hazard structurally impossible
        // (see kernel comment). This removes the per-step drain on the
        // previous step's HBM write-acks — the round-3 bottleneck theory.

        u32* hdst = hb + ((t + 1) & 3) * 16 * UH;
        for (int e = 0; e < ne; ++e) {
            int b = eb[e], co = eco[e], ih = eih[e], gb = egb[e];
            float rz = rec_lds[b * NCP + co] + ebrz[e];
            float rr = rec_lds[b * NCP + HS + co] + ebrr[e];
            float rh = rec_lds[b * NCP + 2 * HS + co] + ebrh[e];
            float z = 1.f / (1.f + __expf(-(xzv[e] + rz)));
            float r = 1.f / (1.f + __expf(-(xrv[e] + rr)));
            float pre = xhv[e] + r * rh;
            float th = 2.f / (1.f + __expf(-2.f * pre)) - 1.f;
            float hn = z * hold[e] + (1.f - z) * th;
            if (tokv[e] == 0) hn = hold[e];            // masked: carry state
            hold[e] = hn;
            u16 hv = f2bf(hn);
            u32 tagged = ((u32)hv << 16) | (u32)(t + 1);
            __hip_atomic_store(hdst + b * UH + ih, tagged, __ATOMIC_RELAXED,
                               __HIP_MEMORY_SCOPE_AGENT);
            out_f32[((size_t)gb * 256 + t) * UH + ih] = hn;
            if (WB16) out_b16[(size_t)(t * 128 + gb) * UH + ih] = hv;
            if (t == 255) h_final[(size_t)gb * UH + ih] = hn;
        }
    }
}

// ---------------------------------------------------------------------------
// launch
// ---------------------------------------------------------------------------
extern "C" void kernel_launch(void* const* d_in, const int* in_sizes, int n_in,
                              void* d_out, int out_size, void* d_ws, size_t ws_size,
                              hipStream_t stream)
{
    const int*   tokens = (const int*)d_in[0];
    const float* emb    = (const float*)d_in[1];
    const float* gamma  = (const float*)d_in[2];
    const float* beta   = (const float*)d_in[3];
    const float* mmean  = (const float*)d_in[4];
    const float* mvar   = (const float*)d_in[5];
    const float* W1     = (const float*)d_in[6];
    const float* U1     = (const float*)d_in[7];
    const float* b1     = (const float*)d_in[8];
    const float* W2     = (const float*)d_in[9];
    const float* U2     = (const float*)d_in[10];
    const float* b2     = (const float*)d_in[11];

    float* out = (float*)d_out;
    char* ws = (char*)d_ws;

    u16* x     = (u16*)(ws + 0);            // 32768*200*2  = 13,107,200
    u16* xw1   = (u16*)(ws + 13107200);     // 32768*1200*2 = 78,643,200
    u16* o1b   = (u16*)(ws + 91750400);     // 32768*400*2  = 26,214,400
    u16* xw2   = (u16*)(ws + 117964800);    // 32768*600*2  = 39,321,600
    u16* W1T   = (u16*)(ws + 157286400);    // 480,000
    u16* W2T   = (u16*)(ws + 157766400);    // 480,000
    u16* U1T   = (u16*)(ws + 158246400);    // 960,000
    u16* U2T   = (u16*)(ws + 159206400);    // 240,000
    u32* hbuf1 = (u32*)(ws + 159446400);    // 8*4*16*400 u32 = 819,200 B
    u32* hbuf2 = (u32*)(ws + 160265600);    // 8*4*16*200 u32 = 409,600 B
    u32* clm1  = (u32*)(ws + 160675200);    // 8 u32
    u32* clm2  = (u32*)(ws + 160675232);    // 8 u32

    float* out2 = out;              // [128,256,200]
    float* out1 = out + 6553600;    // [128,256,400]
    float* h2   = out + 19660800;   // [128,200]
    float* h1   = out + 19686400;   // [128,400]

    prep_kernel<<<5420, 256, 0, stream>>>(W1, W2, U1, U2, W1T, W2T, U1T, U2T,
                                          hbuf1);
    embed_bn_kernel<<<25600, 256, 0, stream>>>(tokens, emb, gamma, beta, mmean,
                                               mvar, x);
    // xw1 = x @ W1 + bi1   ([32768,200]@[200,1200])
    gemm_bias_kernel<200, 7, 232><<<dim3(512, 19), 256, 0, stream>>>(
        x, W1T, b1, xw1, 1200);
    // GRU1: UH=400, G=16 (128 WGs), HS=25, NT=5, NH=13 (3200 u64 slots)
    gru_kernel<400, 16, 13, 424, 25, 75, 80, 5, 2, 2, 13, true><<<128, 256, 0, stream>>>(
        xw1, U1T, b1 + 1200, tokens, out1, o1b, h1, hbuf1, clm1);
    // xw2 = out1 @ W2 + bi2   ([32768,400]@[400,600])
    gemm_bias_kernel<400, 13, 424><<<dim3(512, 10), 256, 0, stream>>>(
        o1b, W2T, b2, xw2, 600);
    // GRU2: UH=200, G=4 (32 WGs), HS=50, NT=10, NH=7 (1600 u64 slots)
    gru_kernel<200, 4, 7, 232, 50, 150, 160, 10, 3, 4, 7, false><<<32, 256, 0, stream>>>(
        xw2, U2T, b2 + 600, tokens, out2, (u16*)nullptr, h2, hbuf2, clm2);
}

// Round 7
// 3097.991 us; speedup vs baseline: 1.2358x; 1.1128x over previous
//
#include <hip/hip_runtime.h>

typedef unsigned int u32;
typedef unsigned short u16;
typedef unsigned long long u64;

typedef __attribute__((ext_vector_type(8))) short bf16x8;
typedef __attribute__((ext_vector_type(4))) float f32x4;

__device__ __forceinline__ u16 f2bf(float f) {
    u32 u = __float_as_uint(f);
    u += 0x7fffu + ((u >> 16) & 1u);
    return (u16)(u >> 16);
}
__device__ __forceinline__ float bf2f(u16 h) {
    return __uint_as_float(((u32)h) << 16);
}

// ---------------------------------------------------------------------------
// prep: convert/transpose weights to bf16, zero tagged h-exchange ring
// (depth-4) and claim counters. Zero extent: 204800 + 102400 + 16 = 307,216.
// ---------------------------------------------------------------------------
__global__ __launch_bounds__(256) void prep_kernel(
    const float* __restrict__ W1, const float* __restrict__ W2,
    const float* __restrict__ U1, const float* __restrict__ U2,
    u16* __restrict__ W1T, u16* __restrict__ W2T,
    u16* __restrict__ U1T, u16* __restrict__ U2T,
    u32* __restrict__ hzero)
{
    int i = blockIdx.x * 256 + threadIdx.x;
    if (i < 240000) { int j = i / 200, k = i - j * 200; W1T[i] = f2bf(W1[k * 1200 + j]); return; }
    i -= 240000;
    if (i < 240000) { int j = i / 400, k = i - j * 400; W2T[i] = f2bf(W2[k * 600 + j]); return; }
    i -= 240000;
    if (i < 480000) { int j = i / 400, k = i - j * 400; U1T[i] = f2bf(U1[k * 1200 + j]); return; }
    i -= 480000;
    if (i < 120000) { int j = i / 200, k = i - j * 200; U2T[i] = f2bf(U2[k * 600 + j]); return; }
    i -= 120000;
    if (i < 307216) hzero[i] = 0u;   // hbuf1 + hbuf2 + claims1 + claims2
}

// ---------------------------------------------------------------------------
// embed + batchnorm -> x bf16, layout [t*128 + b][200]
// ---------------------------------------------------------------------------
__global__ __launch_bounds__(256) void embed_bn_kernel(
    const int* __restrict__ tokens, const float* __restrict__ emb,
    const float* __restrict__ gamma, const float* __restrict__ beta,
    const float* __restrict__ mmean, const float* __restrict__ mvar,
    u16* __restrict__ x)
{
    int gid = blockIdx.x * 256 + threadIdx.x;  // 6,553,600 total
    int r = gid / 200, e = gid - r * 200;
    int t = r >> 7, b = r & 127;               // r = t*128 + b
    int tok = tokens[b * 256 + t];
    float v = (emb[(size_t)tok * 200 + e] - mmean[e]) *
              (1.0f / sqrtf(mvar[e] + 1e-3f)) * gamma[e] + beta[e];
    x[gid] = f2bf(v);
}

// ---------------------------------------------------------------------------
// GEMM: C[M][N] (bf16) = A[M][KEL] (bf16) @ B[KEL][N] + bias, B given as
// BT[N][KEL]. Tile 64x64 per 256-thread WG; MFMA 16x16x32 bf16.
// ---------------------------------------------------------------------------
template<int KEL, int KSTEPS, int KPAD>
__global__ __launch_bounds__(256) void gemm_bias_kernel(
    const u16* __restrict__ A, const u16* __restrict__ BT,
    const float* __restrict__ bias, u16* __restrict__ C, int N)
{
    __shared__ u16 A_lds[64 * KPAD];
    __shared__ u16 B_lds[64 * KPAD];
    const int m0 = blockIdx.x * 64, n0 = blockIdx.y * 64;
    const int tid = threadIdx.x;
    const int lane = tid & 63, wave = tid >> 6;
    const int l15 = lane & 15, lq = lane >> 4;

    for (int idx = tid; idx < 64 * (KPAD / 2); idx += 256) {
        int row = idx / (KPAD / 2), kp = idx % (KPAD / 2);
        int k = kp * 2;
        u32 va = (k < KEL) ? *(const u32*)(A + (size_t)(m0 + row) * KEL + k) : 0u;
        *(u32*)(A_lds + row * KPAD + k) = va;
        int gn = n0 + row;
        u32 vb = (k < KEL && gn < N) ? *(const u32*)(BT + (size_t)gn * KEL + k) : 0u;
        *(u32*)(B_lds + row * KPAD + k) = vb;
    }
    __syncthreads();

    f32x4 acc[4];
    for (int i = 0; i < 4; ++i) acc[i] = (f32x4){0.f, 0.f, 0.f, 0.f};
    for (int ks = 0; ks < KSTEPS; ++ks) {
        bf16x8 a = *(const bf16x8*)(A_lds + (wave * 16 + l15) * KPAD + ks * 32 + lq * 8);
        for (int nt = 0; nt < 4; ++nt) {
            bf16x8 b = *(const bf16x8*)(B_lds + (nt * 16 + l15) * KPAD + ks * 32 + lq * 8);
            acc[nt] = __builtin_amdgcn_mfma_f32_16x16x32_bf16(a, b, acc[nt], 0, 0, 0);
        }
    }
    for (int nt = 0; nt < 4; ++nt) {
        int col = n0 + nt * 16 + l15;
        if (col < N) {
            float bv = bias[col];
            for (int i = 0; i < 4; ++i) {
                int row = m0 + wave * 16 + lq * 4 + i;
                C[(size_t)row * N + col] = f2bf(acc[nt][i] + bv);
            }
        }
    }
}

// ---------------------------------------------------------------------------
// Persistent GRU scan (GRU1), SELF-TAGGED h exchange, DEPTH-4 ring,
// agent-scope ops throughout (round-4 proven). XCD-affinity claiming keeps
// a group's WGs on one XCD (3x HBM-fetch cut, round 3).
// Round-7 micro-opts: tokens staged to LDS once (removes per-step HBM token
// loads from the poll's implicit vmcnt drain); gate phase publishes ALL tags
// before issuing output stores (publishes leave earlier, output acks retire
// in the next poll's shadow).
// WAR safety of the depth-4 ring: two same-address stores are 4 steps
// (>100 VMEM ops) apart > 63-entry in-order vmcnt window.
// ---------------------------------------------------------------------------
template<int UH, int G, int KSTEPS, int KPAD, int HS, int NC, int NCP, int NT,
         int MAXT, int MAXE, int NH, bool WB16>
__global__ __launch_bounds__(256) void gru_kernel(
    const u16* __restrict__ xw,      // [256*128][3*UH] bf16 (row = t*128+b)
    const u16* __restrict__ UT,      // [3*UH][UH] bf16 (transposed U)
    const float* __restrict__ br,    // [3*UH] recurrent bias
    const int* __restrict__ tokens,  // [128][256]
    float* __restrict__ out_f32,     // [128][256][UH]
    u16* __restrict__ out_b16,       // [256*128][UH] or unused
    float* __restrict__ h_final,     // [128][UH]
    u32* __restrict__ hbuf,          // [8][4][16][UH] tagged u32
    u32* __restrict__ claims)        // [8] claim counters (zeroed by prep)
{
    __shared__ u16 U_lds[NCP * KPAD];
    __shared__ u16 h_lds[16 * KPAD];
    __shared__ float rec_lds[16 * NCP];
    __shared__ unsigned char tok_lds[16 * 256];
    __shared__ int claim_s[2];

    const int tid = threadIdx.x;

    // --- XCD-affinity claim (one per WG); deadlock-free by counting argument
    if (tid == 0) {
        u32 xcc;
        asm volatile("s_getreg_b32 %0, hwreg(HW_REG_XCC_ID)" : "=s"(xcc));
        int x = (int)(xcc & 7u);
        int cg = -1, cw = -1;
        for (int a = 0; a < 8; ++a) {
            int gg = (x + a) & 7;
            u32 ww = atomicAdd(&claims[gg], 1u);
            if (ww < (u32)G) { cg = gg; cw = (int)ww; break; }
        }
        claim_s[0] = cg; claim_s[1] = cw;
    }
    __syncthreads();
    const int g = claim_s[0], w = claim_s[1];

    const int b0 = g * 16;
    const int lane = tid & 63, wave = tid >> 6;
    const int l15 = lane & 15, lq = lane >> 4;

    for (int i = tid; i < NCP * KPAD / 2; i += 256) ((u32*)U_lds)[i] = 0u;
    for (int i = tid; i < 16 * KPAD / 2; i += 256) ((u32*)h_lds)[i] = 0u;
    __syncthreads();
    for (int idx = tid; idx < NC * (UH / 2); idx += 256) {
        int c = idx / (UH / 2), kp = idx % (UH / 2);
        int j = (c / HS) * UH + w * HS + (c % HS);
        u32 v = *(const u32*)(UT + (size_t)j * UH + kp * 2);
        *(u32*)(U_lds + c * KPAD + kp * 2) = v;
    }
    // token mask staging (once; covered by the first in-loop barrier)
    for (int i = tid; i < 16 * 256; i += 256) {
        int b = i >> 8, tt = i & 255;
        tok_lds[i] = (tokens[(b0 + b) * 256 + tt] != 0) ? 1 : 0;
    }

    int ne = 0;
    int eb[MAXE], eco[MAXE], eih[MAXE], egb[MAXE], exwoff[MAXE];
    float ebrz[MAXE], ebrr[MAXE], ebrh[MAXE], hold[MAXE];
    for (int u = tid; u < 16 * HS; u += 256) {
        int b = u / HS, co = u % HS;
        int ih = w * HS + co;
        eb[ne] = b; eco[ne] = co; eih[ne] = ih; egb[ne] = b0 + b;
        exwoff[ne] = (b0 + b) * 3 * UH;
        ebrz[ne] = br[ih]; ebrr[ne] = br[UH + ih]; ebrh[ne] = br[2 * UH + ih];
        hold[ne] = 0.f;
        ++ne;
    }

    constexpr int TOT = 16 * UH / 2;   // u64 slots total
    u32 pend0 = 0;
    int soff[NH], loff[NH];
    for (int i = 0; i < NH; ++i) {
        int s = tid + i * 256;
        if (s < TOT) {
            int b = s / (UH / 2), kk = s % (UH / 2);
            soff[i] = b * UH + kk * 2;
            loff[i] = b * KPAD + kk * 2;
            pend0 |= 1u << i;
        } else { soff[i] = 0; loff[i] = 0; }
    }

    u32* hb = hbuf + (size_t)g * 4 * 16 * UH;

    for (int t = 0; t < 256; ++t) {
        // 1. prefetch gate inputs (latency overlaps the poll wait)
        float xzv[MAXE], xrv[MAXE], xhv[MAXE];
        for (int e = 0; e < ne; ++e) {
            const u16* xrow = xw + (size_t)t * (128 * 3 * UH) + exwoff[e];
            xzv[e] = bf2f(xrow[eih[e]]);
            xrv[e] = bf2f(xrow[UH + eih[e]]);
            xhv[e] = bf2f(xrow[2 * UH + eih[e]]);
        }

        // 2. poll tagged h_{t-1} (agent scope), stage to LDS
        const u32* hsrc = hb + (t & 3) * 16 * UH;
        const u32 want = (u32)t & 0xFFFFu;
        u32 pend = pend0;
        while (pend) {
            u64 tmp[NH];
            #pragma unroll
            for (int i = 0; i < NH; ++i)
                if (pend & (1u << i))
                    tmp[i] = __hip_atomic_load((const u64*)(hsrc + soff[i]),
                                               __ATOMIC_RELAXED,
                                               __HIP_MEMORY_SCOPE_AGENT);
            #pragma unroll
            for (int i = 0; i < NH; ++i)
                if (pend & (1u << i)) {
                    u64 v = tmp[i];
                    if ((u32)(v & 0xFFFFu) == want &&
                        ((u32)(v >> 32) & 0xFFFFu) == want) {
                        u32 pk = ((u32)(v >> 16) & 0xFFFFu) | ((u32)(v >> 48) << 16);
                        *(u32*)(h_lds + loff[i]) = pk;
                        pend &= ~(1u << i);
                    }
                }
            if (pend) __builtin_amdgcn_s_sleep(1);
        }
        __syncthreads();

        // 3. rec = h @ U-slice (MFMA 16x16x32)
        f32x4 acc[MAXT];
        for (int ti = 0; ti < MAXT; ++ti) acc[ti] = (f32x4){0.f, 0.f, 0.f, 0.f};
        for (int ks = 0; ks < KSTEPS; ++ks) {
            bf16x8 a = *(const bf16x8*)(h_lds + l15 * KPAD + ks * 32 + lq * 8);
            int ti = 0;
            for (int nt = wave; nt < NT; nt += 4, ++ti) {
                bf16x8 b = *(const bf16x8*)(U_lds + (nt * 16 + l15) * KPAD + ks * 32 + lq * 8);
                acc[ti] = __builtin_amdgcn_mfma_f32_16x16x32_bf16(a, b, acc[ti], 0, 0, 0);
            }
        }
        {
            int ti = 0;
            for (int nt = wave; nt < NT; nt += 4, ++ti)
                for (int i = 0; i < 4; ++i)
                    rec_lds[(lq * 4 + i) * NCP + nt * 16 + l15] = acc[ti][i];
        }
        __syncthreads();

        // 4. gates: compute ALL, publish ALL tags, THEN output stores
        u32* hdst = hb + ((t + 1) & 3) * 16 * UH;
        float hnv[MAXE];
        u32 tgv[MAXE];
        for (int e = 0; e < ne; ++e) {
            int b = eb[e], co = eco[e];
            float rz = rec_lds[b * NCP + co] + ebrz[e];
            float rr = rec_lds[b * NCP + HS + co] + ebrr[e];
            float rh = rec_lds[b * NCP + 2 * HS + co] + ebrh[e];
            float z = 1.f / (1.f + __expf(-(xzv[e] + rz)));
            float r = 1.f / (1.f + __expf(-(xrv[e] + rr)));
            float pre = xhv[e] + r * rh;
            float th = 2.f / (1.f + __expf(-2.f * pre)) - 1.f;
            float hn = z * hold[e] + (1.f - z) * th;
            if (!tok_lds[b * 256 + t]) hn = hold[e];   // masked: carry state
            hold[e] = hn;
            hnv[e] = hn;
            tgv[e] = ((u32)f2bf(hn) << 16) | (u32)(t + 1);
        }
        for (int e = 0; e < ne; ++e)
            __hip_atomic_store(hdst + eb[e] * UH + eih[e], tgv[e],
                               __ATOMIC_RELAXED, __HIP_MEMORY_SCOPE_AGENT);
        for (int e = 0; e < ne; ++e) {
            int gb = egb[e], ih = eih[e];
            out_f32[((size_t)gb * 256 + t) * UH + ih] = hnv[e];
            if (WB16) out_b16[(size_t)(t * 128 + gb) * UH + ih] = (u16)(tgv[e] >> 16);
            if (t == 255) h_final[(size_t)gb * UH + ih] = hnv[e];
        }
    }
}

// ---------------------------------------------------------------------------
// GRU2, exchange-free, register-resident U2. One 512-thread WG per 16-batch
// group (8 WGs). __launch_bounds__(512, 1): 1 block/CU = 2 waves/SIMD ->
// 256-VGPR budget/wave. uf[5][7] (140 VGPR) + acc + prefetch ~= 225 fits.
// (Round 0 failed with (512,2): 2 blocks/CU = 4 waves/SIMD = 128-VGPR cap
// -> uf spilled to scratch; round 1's 256-thread variant needed 280 > the
// 256 architectural VGPR ceiling. This is the untried fitting config.)
// Body identical to the round-0 kernel that passed correctness.
// ---------------------------------------------------------------------------
__global__ __launch_bounds__(512, 1) void gru2_kernel(
    const u16* __restrict__ xw,      // [256*128][600] bf16 (row = t*128+b)
    const u16* __restrict__ UT,      // [600][200] bf16 (transposed U2)
    const float* __restrict__ br,    // [600] recurrent bias
    const int* __restrict__ tokens,  // [128][256]
    float* __restrict__ out_f32,     // [128][256][200]
    float* __restrict__ h_final)     // [128][200]
{
    __shared__ u16 h_lds[16 * 232];          // [batch][k], k=200 holds 1.0
    __shared__ float rec_lds[16 * 616];      // [batch][gatecol 0..607]
    __shared__ unsigned char mask_lds[16 * 256];

    const int g = blockIdx.x;                // 8 groups of 16 batches
    const int b0 = g * 16;
    const int tid = threadIdx.x;             // 0..511 (8 waves)
    const int lane = tid & 63, wave = tid >> 6;
    const int l15 = lane & 15, lq = lane >> 4;

    for (int i = tid; i < 16 * 232 / 2; i += 512) ((u32*)h_lds)[i] = 0u;
    __syncthreads();
    // ones row for bias bake-in (k = 200 stays 1.0: gates write co<200 only)
    if (tid < 16) h_lds[tid * 232 + 200] = (u16)0x3F80;   // bf16 1.0
    for (int i = tid; i < 16 * 256; i += 512) {
        int b = i >> 8, t = i & 255;
        mask_lds[i] = (tokens[(b0 + b) * 256 + t] != 0) ? 1 : 0;
    }

    // persistent U fragments: tile nt = wave*5+it (38 real tiles)
    bf16x8 uf[5][7];
    #pragma unroll
    for (int it = 0; it < 5; ++it) {
        int nt = wave * 5 + it;
        int row = nt * 16 + l15;
        bool rv = (row < 600);
        #pragma unroll
        for (int ks = 0; ks < 7; ++ks) {
            int k0 = ks * 32 + lq * 8;
            bf16x8 v = (bf16x8){0, 0, 0, 0, 0, 0, 0, 0};
            if (rv && k0 < 200)
                v = *(const bf16x8*)(UT + (size_t)row * 200 + k0);
            if (rv && k0 == 200)
                v[0] = (short)f2bf(br[row]);             // bias row (k==200)
            uf[it][ks] = v;
        }
    }

    int be[7], ce[7];
    float hold[7];
    #pragma unroll
    for (int e = 0; e < 7; ++e) {
        int u = tid + e * 512;
        int b = u / 200;
        be[e] = b; ce[e] = u - b * 200;
        hold[e] = 0.f;
    }
    __syncthreads();

    for (int t = 0; t < 256; ++t) {
        // phase 1: prefetch gate inputs
        float xzv[7], xrv[7], xhv[7];
        const u16* xbase = xw + (size_t)t * (128 * 600);
        #pragma unroll
        for (int e = 0; e < 7; ++e) {
            if (tid + e * 512 < 3200) {
                const u16* xrow = xbase + (size_t)(b0 + be[e]) * 600 + ce[e];
                xzv[e] = bf2f(xrow[0]);
                xrv[e] = bf2f(xrow[200]);
                xhv[e] = bf2f(xrow[400]);
            }
        }

        // phase 2: rec = [h,1] @ [U;br]  (MFMA 16x16x32, U from registers)
        f32x4 acc[5];
        #pragma unroll
        for (int it = 0; it < 5; ++it) acc[it] = (f32x4){0.f, 0.f, 0.f, 0.f};
        #pragma unroll
        for (int ks = 0; ks < 7; ++ks) {
            bf16x8 a = *(const bf16x8*)(h_lds + l15 * 232 + ks * 32 + lq * 8);
            #pragma unroll
            for (int it = 0; it < 5; ++it)
                acc[it] = __builtin_amdgcn_mfma_f32_16x16x32_bf16(a, uf[it][ks], acc[it], 0, 0, 0);
        }
        #pragma unroll
        for (int it = 0; it < 5; ++it) {
            int nt = wave * 5 + it;
            if (nt < 38) {
                #pragma unroll
                for (int i = 0; i < 4; ++i)
                    rec_lds[(lq * 4 + i) * 616 + nt * 16 + l15] = acc[it][i];
            }
        }
        __syncthreads();

        // phase 3: gates + state update
        #pragma unroll
        for (int e = 0; e < 7; ++e) {
            if (tid + e * 512 < 3200) {
                int b = be[e], co = ce[e];
                float rz = rec_lds[b * 616 + co];
                float rr = rec_lds[b * 616 + 200 + co];
                float rh = rec_lds[b * 616 + 400 + co];
                float z = 1.f / (1.f + __expf(-(xzv[e] + rz)));
                float r = 1.f / (1.f + __expf(-(xrv[e] + rr)));
                float pre = xhv[e] + r * rh;
                float th = 2.f / (1.f + __expf(-2.f * pre)) - 1.f;
                float hn = z * hold[e] + (1.f - z) * th;
                if (!mask_lds[b * 256 + t]) hn = hold[e];   // masked: carry
                hold[e] = hn;
                h_lds[b * 232 + co] = f2bf(hn);
                out_f32[((size_t)(b0 + b) * 256 + t) * 200 + co] = hn;
                if (t == 255) h_final[(size_t)(b0 + b) * 200 + co] = hn;
            }
        }
        __syncthreads();
    }
}

// ---------------------------------------------------------------------------
// launch
// ---------------------------------------------------------------------------
extern "C" void kernel_launch(void* const* d_in, const int* in_sizes, int n_in,
                              void* d_out, int out_size, void* d_ws, size_t ws_size,
                              hipStream_t stream)
{
    const int*   tokens = (const int*)d_in[0];
    const float* emb    = (const float*)d_in[1];
    const float* gamma  = (const float*)d_in[2];
    const float* beta   = (const float*)d_in[3];
    const float* mmean  = (const float*)d_in[4];
    const float* mvar   = (const float*)d_in[5];
    const float* W1     = (const float*)d_in[6];
    const float* U1     = (const float*)d_in[7];
    const float* b1     = (const float*)d_in[8];
    const float* W2     = (const float*)d_in[9];
    const float* U2     = (const float*)d_in[10];
    const float* b2     = (const float*)d_in[11];

    float* out = (float*)d_out;
    char* ws = (char*)d_ws;

    u16* x     = (u16*)(ws + 0);            // 32768*200*2  = 13,107,200
    u16* xw1   = (u16*)(ws + 13107200);     // 32768*1200*2 = 78,643,200
    u16* o1b   = (u16*)(ws + 91750400);     // 32768*400*2  = 26,214,400
    u16* xw2   = (u16*)(ws + 117964800);    // 32768*600*2  = 39,321,600
    u16* W1T   = (u16*)(ws + 157286400);    // 480,000
    u16* W2T   = (u16*)(ws + 157766400);    // 480,000
    u16* U1T   = (u16*)(ws + 158246400);    // 960,000
    u16* U2T   = (u16*)(ws + 159206400);    // 240,000
    u32* hbuf1 = (u32*)(ws + 159446400);    // 8*4*16*400 u32 = 819,200 B
    u32* hbuf2 = (u32*)(ws + 160265600);    // 8*4*16*200 u32 = 409,600 B (idle)
    u32* clm1  = (u32*)(ws + 160675200);    // 8 u32
    u32* clm2  = (u32*)(ws + 160675232);    // 8 u32

    float* out2 = out;              // [128,256,200]
    float* out1 = out + 6553600;    // [128,256,400]
    float* h2   = out + 19660800;   // [128,200]
    float* h1   = out + 19686400;   // [128,400]

    prep_kernel<<<5420, 256, 0, stream>>>(W1, W2, U1, U2, W1T, W2T, U1T, U2T,
                                          hbuf1);
    embed_bn_kernel<<<25600, 256, 0, stream>>>(tokens, emb, gamma, beta, mmean,
                                               mvar, x);
    // xw1 = x @ W1 + bi1   ([32768,200]@[200,1200])
    gemm_bias_kernel<200, 7, 232><<<dim3(512, 19), 256, 0, stream>>>(
        x, W1T, b1, xw1, 1200);
    // GRU1: UH=400, G=16 (128 WGs), HS=25, NT=5, NH=13 (3200 u64 slots)
    gru_kernel<400, 16, 13, 424, 25, 75, 80, 5, 2, 2, 13, true><<<128, 256, 0, stream>>>(
        xw1, U1T, b1 + 1200, tokens, out1, o1b, h1, hbuf1, clm1);
    // xw2 = out1 @ W2 + bi2   ([32768,400]@[400,600])
    gemm_bias_kernel<400, 13, 424><<<dim3(512, 10), 256, 0, stream>>>(
        o1b, W2T, b2, xw2, 600);
    // GRU2: exchange-free, 8 WGs x 512 threads, register-resident U2
    gru2_kernel<<<8, 512, 0, stream>>>(xw2, U2T, b2 + 600, tokens, out2, h2);
    (void)hbuf2; (void)clm2;
}